// Round 11
// baseline (74860.944 us; speedup 1.0000x reference)
//
#include <hip/hip_runtime.h>
#include <hip/hip_bf16.h>
#include <cstdint>

#define B_ 128
#define T_ 256
#define C_ 512
#define H_ 2048
#define NWG 256
#define NTHR 256
#define NGROUP 8
#define GSIZE 32        // WGs per row-group
#define M_ 16           // batch rows per group
#define FSTRIDE 16      // flag padding (dwords) -> 64 B per flag
#define RSU1 132        // atile row stride in ull
#define RSS1 528        // row stride in shorts
// DT = (1/(T-1))/N_SUB = 1/765
#define DT_F 0.0013071895424836601f

typedef __bf16 bf16x8 __attribute__((ext_vector_type(8)));
typedef short s16x8 __attribute__((ext_vector_type(8)));
typedef float f32x4 __attribute__((ext_vector_type(4)));
typedef unsigned long long ull;

// ---------------- workspace layout (bytes) — 9.03 MB total ----------------
enum : size_t {
  OFF_FLAGS = 0,                                     // 16 KB
  OFF_B31   = 16384,                                 // b31 fp32 (8 KB)
  OFF_W31P  = 32768,                                 // W31 = W3@W1 packed bf16 (8 MB)
  OFF_H1    = OFF_W31P + (size_t)H_ * H_ * 2,        // 512 KB
  OFF_H2    = OFF_H1   + (size_t)NGROUP * M_ * H_ * 2,
  WS_END    = OFF_H2   + (size_t)NGROUP * M_ * H_ * 2   // ~9.03 MB  (< 13.4 MB proven)
};

__device__ __forceinline__ bf16x8 ld_frag(const unsigned short* p) {
  s16x8 v = *reinterpret_cast<const s16x8*>(p);
  return __builtin_bit_cast(bf16x8, v);
}
__device__ __forceinline__ bf16x8 lds_frag(const unsigned short* p) {
  s16x8 v = *reinterpret_cast<const s16x8*>(p);
  return __builtin_bit_cast(bf16x8, v);
}
__device__ __forceinline__ void st_coh16(unsigned short* p, unsigned short v) {
  __hip_atomic_store(p, v, __ATOMIC_RELAXED, __HIP_MEMORY_SCOPE_AGENT);
}
__device__ __forceinline__ f32x4 mfma16(bf16x8 a, bf16x8 b, f32x4 c) {
  return __builtin_amdgcn_mfma_f32_16x16x32_bf16(a, b, c, 0, 0, 0);
}
__device__ __forceinline__ unsigned short tobf(float f) {
  return __builtin_bit_cast(unsigned short, (__bf16)f);
}
__device__ __forceinline__ float fast_tanh(float v) {
  float e = __expf(2.0f * v);
  return 1.0f - 2.0f / (e + 1.0f);
}

// drain own LDS ops, raw barrier (keeps vmem loads in flight) — r7-proven
#define LGKM0_BAR() do {                                   \
  asm volatile("s_waitcnt lgkmcnt(0)" ::: "memory");       \
  __builtin_amdgcn_s_barrier();                            \
} while (0)

// ---------------- prologue kernels ----------------
__global__ void init_flags_k(unsigned* f) {
  int i = blockIdx.x * 256 + threadIdx.x;
  if (i < NGROUP * GSIZE * FSTRIDE) f[i] = 0u;
}

// W31[h][n] = sum_c W3[h][c]*W1[c][n] (fp32), written bf16 at the packed
// B-fragment index (K=2048, N=2048). Tail blocks: b31 = b3@W1 (fp32).
// Packed index verified against validated swizzle layout:
// idx = (((n>>4)*64 + (h>>5))*64 + ((((h>>3)&3)<<4)|(n&15)))*8 + (h&7)
__global__ void w31_k(const float* __restrict__ W3, const float* __restrict__ W1,
                      const float* __restrict__ b3, unsigned short* __restrict__ W31p,
                      float* __restrict__ b31) {
  int bid = blockIdx.x, t = threadIdx.x;
  if (bid < H_ * 8) {
    int h = bid >> 3, n = (bid & 7) * 256 + t;
    float acc = 0.f;
    #pragma unroll 4
    for (int c = 0; c < C_; ++c)
      acc = fmaf(W3[(size_t)h * C_ + c], W1[(size_t)c * H_ + n], acc);
    int kb = h >> 5, j = h & 7;
    int l = (((h >> 3) & 3) << 4) | (n & 15);
    int nt = n >> 4;
    W31p[(((size_t)nt * 64 + kb) * 64 + l) * 8 + j] = tobf(acc);
  } else {
    int n = (bid - H_ * 8) * 256 + t;
    float acc = 0.f;
    #pragma unroll 4
    for (int c = 0; c < C_; ++c)
      acc = fmaf(b3[c], W1[(size_t)c * H_ + n], acc);
    b31[n] = acc;
  }
}

// ---------------- split-phase group barrier (baseline-proven) ----------------
__device__ __forceinline__ void bar_arrive(unsigned* gf, int gn, unsigned gen) {
  asm volatile("s_waitcnt vmcnt(0)" ::: "memory");
  __syncthreads();
  if (threadIdx.x == 0)
    __hip_atomic_store(&gf[gn * FSTRIDE], gen, __ATOMIC_RELAXED, __HIP_MEMORY_SCOPE_AGENT);
}
__device__ __forceinline__ void bar_wait(unsigned* gf, unsigned gen) {
  if (threadIdx.x < GSIZE) {
    while (__hip_atomic_load(&gf[threadIdx.x * FSTRIDE], __ATOMIC_RELAXED,
                             __HIP_MEMORY_SCOPE_AGENT) < gen)
      __builtin_amdgcn_s_sleep(1);
  }
  __syncthreads();
}

// ---------------- staging (baseline-proven) ----------------
__device__ __forceinline__ void issue_c(const ull* __restrict__ g, int tid, ull v[8]) {
  #pragma unroll
  for (int j = 0; j < 8; ++j) {
    int i = j * NTHR + tid;
    v[j] = __hip_atomic_load(g + (size_t)(i >> 7) * 512 + (i & 127),
                             __ATOMIC_RELAXED, __HIP_MEMORY_SCOPE_AGENT);
  }
}
__device__ __forceinline__ void commit(ull* __restrict__ lds, int tid, const ull v[8]) {
  #pragma unroll
  for (int j = 0; j < 8; ++j) {
    int i = j * NTHR + tid;
    lds[(i >> 7) * RSU1 + (i & 127)] = v[j];
  }
}

#define L2CHUNK(c, buf) {                                                     \
  const unsigned short* al = (const unsigned short*)atile[buf] + llo * RSS1 + lhi * 8; \
  _Pragma("unroll")                                                           \
  for (int jj = 0; jj < 8; ++jj) {                                            \
    acc0 = mfma16(lds_frag(al + (2 * jj) * 32),     w2r[(c) * 16 + 2 * jj],     acc0); \
    acc1 = mfma16(lds_frag(al + (2 * jj + 1) * 32), w2r[(c) * 16 + 2 * jj + 1], acc1); \
  } }

// fused K (h2@W31, streamed wf) + local z (h2@W3, wave K-split, w3r regs)
#define KZCHUNK(c, buf) {                                                     \
  const unsigned short* al = (const unsigned short*)atile[buf] + llo * RSS1 + lhi * 8; \
  _Pragma("unroll")                                                           \
  for (int jj = 0; jj < 8; ++jj) {                                            \
    aK0 = mfma16(lds_frag(al + (2 * jj) * 32),     wf[2 * jj],     aK0);      \
    aK1 = mfma16(lds_frag(al + (2 * jj + 1) * 32), wf[2 * jj + 1], aK1);      \
  }                                                                           \
  _Pragma("unroll")                                                           \
  for (int jj = 0; jj < 2; ++jj) {                                            \
    az0 = mfma16(lds_frag(al + (wave * 4 + 2 * jj) * 32),     w3r[(c) * 4 + 2 * jj],     az0); \
    az1 = mfma16(lds_frag(al + (wave * 4 + 2 * jj + 1) * 32), w3r[(c) * 4 + 2 * jj + 1], az1); \
  } }

// ---------------- persistent ODE kernel: projected-RK4, 2 barriers/eval ------
// Y1 = y@W1 (fp32 regs) replaces the u exchange: h1 = tanh(Y1 + alpha*K + b1)
// where K = h2@W31 + b31 is local after the h2 exchange. C-space y/out path is
// structurally identical to baseline (local 16-col z via w3r). Weights w2r/w3r
// gathered once from fp32 inputs (no packed W1/W2/W3 in ws -> 9 MB footprint).
__global__ __launch_bounds__(NTHR, 1) void ode_persist_k(
    const float* __restrict__ x, const float* __restrict__ W1f,
    const float* __restrict__ W2f, const float* __restrict__ W3f,
    const float* __restrict__ b1, const float* __restrict__ b2,
    const float* __restrict__ b3v, float* __restrict__ out,
    unsigned char* __restrict__ ws) {
  const int wg = blockIdx.x, tid = threadIdx.x;
  const int g = wg >> 5, gn = wg & 31;
  const int wave = tid >> 6, lane = tid & 63;
  const int lhi = lane >> 4, llo = lane & 15;

  unsigned* gflags = (unsigned*)(ws + OFF_FLAGS) + g * GSIZE * FSTRIDE;
  const float* b31 = (const float*)(ws + OFF_B31);
  const unsigned short* W31p = (const unsigned short*)(ws + OFF_W31P);
  const ull* h1_u = (const ull*)(ws + OFF_H1) + (size_t)g * (M_ * H_ / 4);
  const ull* h2_u = (const ull*)(ws + OFF_H2) + (size_t)g * (M_ * H_ / 4);
  unsigned short* h1_s = (unsigned short*)(ws + OFF_H1) + (size_t)g * M_ * H_;
  unsigned short* h2_s = (unsigned short*)(ws + OFF_H2) + (size_t)g * M_ * H_;

  __shared__ alignas(16) ull atile[2][M_ * RSU1];   // 33 KB (init: x scratch)
  __shared__ float red[4][256];
  __shared__ float ytile[256], k1t[256], k2t[256], k3t[256];

  const int n16 = gn * 4 + wave;
  const int col = n16 * 16 + llo;
  const unsigned short* bp31 = W31p + (size_t)n16 * 64 * 512 + lane * 8;

  // ---- init: stage bf16-rounded x rows in LDS; ytile/out ----
  {
    float* xs = (float*)atile;            // 32 KB scratch (atile reused later)
    #pragma unroll 4
    for (int k = 0; k < 32; ++k) {
      int i = k * NTHR + tid;             // 0..8191 = row*512+c
      int row = i >> 9, c = i & 511;
      float v = x[(size_t)(g * M_ + row) * (T_ * C_) + c];
      xs[i] = (float)(__bf16)v;           // mimic baseline's bf16 u-rounding
    }
    int row = tid >> 4, c16 = tid & 15;
    int b = g * M_ + row;
    float v = x[(size_t)b * (T_ * C_) + gn * 16 + c16];
    ytile[tid] = v;
    out[(size_t)b * (T_ * C_) + gn * 16 + c16] = v;
  }
  __syncthreads();

  // ---- one-time: gather register-resident W2 / W3 slices from fp32 inputs ----
  bf16x8 w2r[64], w3r[16];
  #pragma unroll
  for (int kb = 0; kb < 64; ++kb) {
    bf16x8 tfr;
    #pragma unroll
    for (int j = 0; j < 8; ++j)
      tfr[j] = (__bf16)W2f[(size_t)(kb * 32 + lhi * 8 + j) * H_ + col];
    w2r[kb] = tfr;
  }
  #pragma unroll
  for (int q = 0; q < 16; ++q) {
    int kb = (q >> 2) * 16 + wave * 4 + (q & 3);
    bf16x8 tfr;
    #pragma unroll
    for (int j = 0; j < 8; ++j)
      tfr[j] = (__bf16)W3f[(size_t)(kb * 32 + lhi * 8 + j) * C_ + gn * 16 + llo];
    w3r[q] = tfr;
  }

  const float bb1  = b1[col];
  const float bb2  = b2[col];
  const float bb3  = b3v[gn * 16 + llo];
  const float bb31 = b31[col];

  // ---- one-time: Y1 = bf16(x0 rows) @ bf16(W1 cols), scalar fp32 ----
  f32x4 Y1 = {0.f, 0.f, 0.f, 0.f};
  {
    const float* xs = (const float*)atile;
    for (int c = 0; c < C_; ++c) {
      float wv = (float)(__bf16)W1f[(size_t)c * H_ + col];
      #pragma unroll
      for (int r = 0; r < 4; ++r)
        Y1[r] = fmaf(xs[(lhi * 4 + r) * 512 + c], wv, Y1[r]);
    }
  }
  __syncthreads();                        // xs scratch dead; atile free for loop

  f32x4 Kp = {0.f, 0.f, 0.f, 0.f};        // K of previous stage (unused at st 0)
  f32x4 SK = {0.f, 0.f, 0.f, 0.f};        // projected RK4 accumulator
  unsigned gen = 0;
  ull va[8], vb[8];

  #pragma unroll 1
  for (int t = 0; t < T_ - 1; ++t) {
    #pragma unroll 1
    for (int sub = 0; sub < 3; ++sub) {
      #pragma unroll 1
      for (int st = 0; st < 4; ++st) {
        // ===== LOCAL: h1 = tanh(Y1 + alpha*Kp + b1) — no exchange =====
        {
          const float alpha = (st == 0) ? 0.0f : (st == 3 ? DT_F : 0.5f * DT_F);
          #pragma unroll
          for (int r = 0; r < 4; ++r) {
            float av = Y1[r] + alpha * Kp[r] + bb1;
            st_coh16(&h1_s[(lhi * 4 + r) * H_ + col], tobf(fast_tanh(av)));
          }
        }
        bar_arrive(gflags, gn, ++gen);
        bar_wait(gflags, gen);

        // ===== layer 2: h2 = tanh(h1@W2+b2), weights in regs (baseline) =====
        {
          f32x4 acc0 = {0.f, 0.f, 0.f, 0.f}, acc1 = {0.f, 0.f, 0.f, 0.f};
          issue_c(h1_u,       tid, va);
          issue_c(h1_u + 128, tid, vb);
          commit(atile[0], tid, va);
          LGKM0_BAR();
          issue_c(h1_u + 256, tid, va);
          L2CHUNK(0, 0);
          commit(atile[1], tid, vb);
          LGKM0_BAR();
          issue_c(h1_u + 384, tid, vb);
          L2CHUNK(1, 1);
          commit(atile[0], tid, va);
          LGKM0_BAR();
          L2CHUNK(2, 0);
          commit(atile[1], tid, vb);
          LGKM0_BAR();
          L2CHUNK(3, 1);
          f32x4 a = acc0 + acc1;
          #pragma unroll
          for (int r = 0; r < 4; ++r)
            st_coh16(&h2_s[(lhi * 4 + r) * H_ + col], tobf(fast_tanh(a[r] + bb2)));
        }
        bar_arrive(gflags, gn, ++gen);
        bar_wait(gflags, gen);

        // ===== K = h2@W31+b31 (streamed wf) + local z = h2@W3 + RK4 =====
        {
          f32x4 aK0 = {0.f, 0.f, 0.f, 0.f}, aK1 = {0.f, 0.f, 0.f, 0.f};
          f32x4 az0 = {0.f, 0.f, 0.f, 0.f}, az1 = {0.f, 0.f, 0.f, 0.f};
          bf16x8 wf[16];
          issue_c(h2_u,       tid, va);
          issue_c(h2_u + 128, tid, vb);
          #pragma unroll
          for (int kb = 0; kb < 16; ++kb) wf[kb] = ld_frag(bp31 + kb * 512);
          commit(atile[0], tid, va);
          LGKM0_BAR();
          issue_c(h2_u + 256, tid, va);
          KZCHUNK(0, 0);
          #pragma unroll
          for (int kb = 0; kb < 16; ++kb) wf[kb] = ld_frag(bp31 + (16 + kb) * 512);
          commit(atile[1], tid, vb);
          LGKM0_BAR();
          issue_c(h2_u + 384, tid, vb);
          KZCHUNK(1, 1);
          #pragma unroll
          for (int kb = 0; kb < 16; ++kb) wf[kb] = ld_frag(bp31 + (32 + kb) * 512);
          commit(atile[0], tid, va);
          LGKM0_BAR();
          KZCHUNK(2, 0);
          #pragma unroll
          for (int kb = 0; kb < 16; ++kb) wf[kb] = ld_frag(bp31 + (48 + kb) * 512);
          commit(atile[1], tid, vb);
          LGKM0_BAR();
          KZCHUNK(3, 1);

          // projected K for next stage + RK4 bookkeeping
          f32x4 Kc;
          #pragma unroll
          for (int r = 0; r < 4; ++r) Kc[r] = aK0[r] + aK1[r] + bb31;
          const float wgt = (st == 0 || st == 3) ? 1.0f : 2.0f;
          #pragma unroll
          for (int r = 0; r < 4; ++r) SK[r] += wgt * Kc[r];
          Kp = Kc;

          // local z (C-space) -> RK4 y/out path, structurally = baseline
          f32x4 a = az0 + az1;
          #pragma unroll
          for (int r = 0; r < 4; ++r) red[wave][(lhi * 4 + r) * 16 + llo] = a[r];
          __syncthreads();
          if (wave == 0) {
            const float dt = DT_F;
            #pragma unroll
            for (int r = 0; r < 4; ++r) {
              int row = lhi * 4 + r;
              int i = row * 16 + llo;
              float z = red[0][i] + red[1][i] + red[2][i] + red[3][i] + bb3;
              if (st == 0)      k1t[i] = z;
              else if (st == 1) k2t[i] = z;
              else if (st == 2) k3t[i] = z;
              else {
                float yn = ytile[i] + (dt * (1.0f / 6.0f)) *
                           (k1t[i] + 2.f * k2t[i] + 2.f * k3t[i] + z);
                ytile[i] = yn;
                if (sub == 2)
                  out[(size_t)(g * M_ + row) * (T_ * C_) + (size_t)(t + 1) * C_ + gn * 16 + llo] = yn;
              }
            }
          }
          if (st == 3) {        // close the projected RK4 step
            #pragma unroll
            for (int r = 0; r < 4; ++r) { Y1[r] += (DT_F * (1.0f / 6.0f)) * SK[r]; SK[r] = 0.f; }
          }
        }
        // no barrier here: next LOCAL phase is register-only (Y1, Kp)
      }
    }
  }
}

// ---------------- host ----------------
extern "C" void kernel_launch(void* const* d_in, const int* in_sizes, int n_in,
                              void* d_out, int out_size, void* d_ws, size_t ws_size,
                              hipStream_t stream) {
  (void)in_sizes; (void)n_in; (void)out_size; (void)ws_size;
  const float* x  = (const float*)d_in[0];
  const float* W1 = (const float*)d_in[1];
  const float* b1 = (const float*)d_in[2];
  const float* W2 = (const float*)d_in[3];
  const float* b2 = (const float*)d_in[4];
  const float* W3 = (const float*)d_in[5];
  const float* b3 = (const float*)d_in[6];
  float* out = (float*)d_out;
  unsigned char* ws = (unsigned char*)d_ws;

  init_flags_k<<<16, 256, 0, stream>>>((unsigned*)(ws + OFF_FLAGS));
  // W31 = W3@W1 (packed bf16 B-fragments) + b31 = b3@W1
  w31_k<<<H_ * 8 + 8, 256, 0, stream>>>(W3, W1, b3, (unsigned short*)(ws + OFF_W31P),
                                        (float*)(ws + OFF_B31));

  ode_persist_k<<<NWG, NTHR, 0, stream>>>(x, W1, W2, W3, b1, b2, b3, out, ws);
}

// Round 12
// 43941.708 us; speedup vs baseline: 1.7036x; 1.7036x over previous
//
#include <hip/hip_runtime.h>
#include <hip/hip_bf16.h>
#include <cstdint>

#define B_ 128
#define T_ 256
#define C_ 512
#define H_ 2048
#define NWG 256
#define NTHR 256
#define NGROUP 8
#define GSIZE 32        // WGs per row-group
#define M_ 16           // batch rows per group
#define FSTRIDE 16      // flag padding (dwords) -> 64 B per flag
#define RSU1 132        // atile row stride in ull: 264 dw == 8 mod 32 -> uniform banks for b128
#define RSS1 528        // row stride in shorts
// DT = (1/(T-1))/N_SUB = 1/765
#define DT_F 0.0013071895424836601f

typedef __bf16 bf16x8 __attribute__((ext_vector_type(8)));
typedef short s16x8 __attribute__((ext_vector_type(8)));
typedef float f32x4 __attribute__((ext_vector_type(4)));
typedef unsigned long long ull;

// ---------------- workspace layout (bytes) ----------------
enum : size_t {
  OFF_FLAGS = 0,                                    // 8 groups * 32 flags * 64 B
  OFF_W1P = 32768,
  OFF_W2P = OFF_W1P + (size_t)C_ * H_ * 2,          // 2 MB
  OFF_W3P = OFF_W2P + (size_t)H_ * H_ * 2,          // 8 MB
  OFF_U   = OFF_W3P + (size_t)H_ * C_ * 2,          // 2 MB
  OFF_H1  = OFF_U   + (size_t)NGROUP * M_ * C_ * 2, // 128 KB
  OFF_H2  = OFF_H1  + (size_t)NGROUP * M_ * H_ * 2, // 512 KB
  WS_END  = OFF_H2  + (size_t)NGROUP * M_ * H_ * 2  // ~13.4 MB
};

__device__ __forceinline__ bf16x8 ld_frag(const unsigned short* p) {   // cached (weights)
  s16x8 v = *reinterpret_cast<const s16x8*>(p);
  return __builtin_bit_cast(bf16x8, v);
}
__device__ __forceinline__ bf16x8 lds_frag(const unsigned short* p) {  // ds_read_b128
  s16x8 v = *reinterpret_cast<const s16x8*>(p);
  return __builtin_bit_cast(bf16x8, v);
}
__device__ __forceinline__ void st_coh16(unsigned short* p, unsigned short v) {
  __hip_atomic_store(p, v, __ATOMIC_RELAXED, __HIP_MEMORY_SCOPE_AGENT);
}
__device__ __forceinline__ f32x4 mfma16(bf16x8 a, bf16x8 b, f32x4 c) {
  return __builtin_amdgcn_mfma_f32_16x16x32_bf16(a, b, c, 0, 0, 0);
}
__device__ __forceinline__ unsigned short tobf(float f) {
  return __builtin_bit_cast(unsigned short, (__bf16)f);
}
__device__ __forceinline__ float fast_tanh(float v) {
  float e = __expf(2.0f * v);
  return 1.0f - 2.0f / (e + 1.0f);
}

// ---------------- prologue kernels ----------------
__global__ void init_flags_k(unsigned* f) {
  int i = blockIdx.x * 256 + threadIdx.x;
  if (i < NGROUP * GSIZE * FSTRIDE) f[i] = 0u;
}

// Pack W[K][N] fp32 -> bf16 in MFMA B-fragment order (validated rounds 1-4):
// packed[((nt*(K/32)+kb)*64 + lane)*8 + j] = W[kb*32 + (lane>>4)*8 + j][nt*16 + (lane&15)]
__global__ void swizzle_w_k(const float* __restrict__ W, unsigned short* __restrict__ Wp,
                            int N, int kblog) {
  int idx = blockIdx.x * 256 + threadIdx.x;
  int j = idx & 7;
  int l = (idx >> 3) & 63;
  int rem = idx >> 9;
  int kb = rem & ((1 << kblog) - 1);
  int nt = rem >> kblog;
  int k = kb * 32 + ((l >> 4) << 3) + j;
  int n = (nt << 4) + (l & 15);
  Wp[idx] = tobf(W[(size_t)k * N + n]);
}

// ---------------- split-phase group barrier (32 WGs), MALL-coherent padded flags ----
__device__ __forceinline__ void bar_arrive(unsigned* gf, int gn, unsigned gen) {
  asm volatile("s_waitcnt vmcnt(0)" ::: "memory");   // coherent stores drained
  __syncthreads();                                   // all waves drained
  if (threadIdx.x == 0)
    __hip_atomic_store(&gf[gn * FSTRIDE], gen, __ATOMIC_RELAXED, __HIP_MEMORY_SCOPE_AGENT);
}
__device__ __forceinline__ void bar_wait(unsigned* gf, unsigned gen) {
  if (threadIdx.x < GSIZE) {
    while (__hip_atomic_load(&gf[threadIdx.x * FSTRIDE], __ATOMIC_RELAXED,
                             __HIP_MEMORY_SCOPE_AGENT) < gen)
      __builtin_amdgcn_s_sleep(1);
  }
  __syncthreads();
}

// ---------------- staging: batched coherent loads + deferred LDS commit ----------------
// chunk = 16 rows x 128 ull; 256 threads x 8 ull each.
__device__ __forceinline__ void issue_u(const ull* __restrict__ g, int tid, ull v[8]) {
  #pragma unroll
  for (int j = 0; j < 8; ++j)     // u is contiguous: 16 rows x 128 ull
    v[j] = __hip_atomic_load(g + j * NTHR + tid, __ATOMIC_RELAXED, __HIP_MEMORY_SCOPE_AGENT);
}
__device__ __forceinline__ void issue_c(const ull* __restrict__ g, int tid, ull v[8]) {
  #pragma unroll
  for (int j = 0; j < 8; ++j) {   // h rows stride 512 ull; chunk = 128 ull of each row
    int i = j * NTHR + tid;
    v[j] = __hip_atomic_load(g + (size_t)(i >> 7) * 512 + (i & 127),
                             __ATOMIC_RELAXED, __HIP_MEMORY_SCOPE_AGENT);
  }
}
__device__ __forceinline__ void commit(ull* __restrict__ lds, int tid, const ull v[8]) {
  #pragma unroll
  for (int j = 0; j < 8; ++j) {
    int i = j * NTHR + tid;
    lds[(i >> 7) * RSU1 + (i & 127)] = v[j];
  }
}

// compile-time-indexed compute macros (keep w2r/w3r register-resident!)
#define L2CHUNK(c, buf) {                                                     \
  const unsigned short* al = (const unsigned short*)atile[buf] + llo * RSS1 + lhi * 8; \
  _Pragma("unroll")                                                           \
  for (int jj = 0; jj < 8; ++jj) {                                            \
    acc0 = mfma16(lds_frag(al + (2 * jj) * 32),     w2r[(c) * 16 + 2 * jj],     acc0); \
    acc1 = mfma16(lds_frag(al + (2 * jj + 1) * 32), w2r[(c) * 16 + 2 * jj + 1], acc1); \
  } }

#define L3CHUNK(c, buf) {                                                     \
  const unsigned short* al = (const unsigned short*)atile[buf] + llo * RSS1 + lhi * 8; \
  _Pragma("unroll")                                                           \
  for (int jj = 0; jj < 2; ++jj) {                                            \
    acc0 = mfma16(lds_frag(al + (wave * 4 + 2 * jj) * 32),     w3r[(c) * 4 + 2 * jj],     acc0); \
    acc1 = mfma16(lds_frag(al + (wave * 4 + 2 * jj + 1) * 32), w3r[(c) * 4 + 2 * jj + 1], acc1); \
  } }

// ---------------- persistent ODE kernel ----------------
// 8 groups x 32 WGs. Group g owns batch rows [16g,16g+16). gn%8 -> XCD weight affinity.
__global__ __launch_bounds__(NTHR, 1) void ode_persist_k(
    const float* __restrict__ x, const float* __restrict__ b1,
    const float* __restrict__ b2, const float* __restrict__ b3,
    float* __restrict__ out, unsigned char* __restrict__ ws) {
  const int wg = blockIdx.x, tid = threadIdx.x;
  const int g = wg >> 5, gn = wg & 31;
  const int wave = tid >> 6, lane = tid & 63;
  const int lhi = lane >> 4, llo = lane & 15;

  unsigned* gflags = (unsigned*)(ws + OFF_FLAGS) + g * GSIZE * FSTRIDE;
  const unsigned short* W1p = (const unsigned short*)(ws + OFF_W1P);
  const unsigned short* W2p = (const unsigned short*)(ws + OFF_W2P);
  const unsigned short* W3p = (const unsigned short*)(ws + OFF_W3P);
  const ull* ubuf_u = (const ull*)(ws + OFF_U)  + (size_t)g * (M_ * C_ / 4);
  const ull* h1_u   = (const ull*)(ws + OFF_H1) + (size_t)g * (M_ * H_ / 4);
  const ull* h2_u   = (const ull*)(ws + OFF_H2) + (size_t)g * (M_ * H_ / 4);
  unsigned short* ubuf_s = (unsigned short*)(ws + OFF_U)  + (size_t)g * M_ * C_;
  unsigned short* h1_s   = (unsigned short*)(ws + OFF_H1) + (size_t)g * M_ * H_;
  unsigned short* h2_s   = (unsigned short*)(ws + OFF_H2) + (size_t)g * M_ * H_;

  __shared__ alignas(16) ull atile[2][M_ * RSU1];   // 2 x 16.5 KB
  __shared__ float red[4][256];
  __shared__ float ytile[256], k1t[256], k2t[256], k3t[256];

  // weight bases (B-fragment layout)
  const int n16 = gn * 4 + wave;                    // layers 1,2 column tile
  const unsigned short* bp1 = W1p + (size_t)n16 * 16 * 512 + lane * 8;
  const unsigned short* bp2 = W2p + (size_t)n16 * 64 * 512 + lane * 8;
  const unsigned short* bp3 = W3p + (size_t)gn  * 64 * 512 + lane * 8;

  // ---- register-resident W2 (256 VGPR) and W3 (64 VGPR) slices ----
  bf16x8 w2r[64], w3r[16];
  #pragma unroll
  for (int kb = 0; kb < 64; ++kb) w2r[kb] = ld_frag(bp2 + kb * 512);
  #pragma unroll
  for (int q = 0; q < 16; ++q)    // q = c*4+jj -> global kb = c*16 + wave*4 + jj
    w3r[q] = ld_frag(bp3 + ((q >> 2) * 16 + wave * 4 + (q & 3)) * 512);

  // biases: fixed per lane -> hoist to registers
  const float bb1 = b1[n16 * 16 + llo];
  const float bb2 = b2[n16 * 16 + llo];
  const float bb3 = b3[gn * 16 + llo];

  // ---- init: y tile from x, out[:,0,:], ubuf = bf16(y) ----
  {
    int row = tid >> 4, c16 = tid & 15;
    int col = gn * 16 + c16;
    int b = g * M_ + row;
    float v = x[(size_t)b * (T_ * C_) + col];
    ytile[tid] = v;
    out[(size_t)b * (T_ * C_) + col] = v;
    st_coh16(&ubuf_s[row * C_ + col], tobf(v));
  }
  unsigned gen = 0;
  bar_arrive(gflags, gn, ++gen);
  bar_wait(gflags, gen);

  ull va[8], vb[8];
  #pragma unroll 1
  for (int t = 0; t < T_ - 1; ++t) {
    #pragma unroll 1
    for (int sub = 0; sub < 3; ++sub) {
      #pragma unroll 1
      for (int st = 0; st < 4; ++st) {
        // ================= layer 1: [16x512]@[512x2048], tanh =================
        {
          issue_u(ubuf_u, tid, va);
          bf16x8 w1f[16];                       // W1 streamed: L2-hit, hidden by u's MALL RT
          #pragma unroll
          for (int kb = 0; kb < 16; ++kb) w1f[kb] = ld_frag(bp1 + kb * 512);
          commit(atile[0], tid, va);
          __syncthreads();
          f32x4 acc0 = {0.f, 0.f, 0.f, 0.f}, acc1 = {0.f, 0.f, 0.f, 0.f};
          const unsigned short* al = (const unsigned short*)atile[0] + llo * RSS1 + lhi * 8;
          #pragma unroll
          for (int jj = 0; jj < 8; ++jj) {
            acc0 = mfma16(lds_frag(al + (2 * jj) * 32),     w1f[2 * jj],     acc0);
            acc1 = mfma16(lds_frag(al + (2 * jj + 1) * 32), w1f[2 * jj + 1], acc1);
          }
          f32x4 a = acc0 + acc1;
          const int col = n16 * 16 + llo;
          #pragma unroll
          for (int r = 0; r < 4; ++r)
            st_coh16(&h1_s[(lhi * 4 + r) * H_ + col], tobf(fast_tanh(a[r] + bb1)));
        }
        bar_arrive(gflags, gn, ++gen);
        bar_wait(gflags, gen);

        // ========== layer 2: [16x2048]@[2048x2048], tanh, weights in VGPRs ==========
        {
          f32x4 acc0 = {0.f, 0.f, 0.f, 0.f}, acc1 = {0.f, 0.f, 0.f, 0.f};
          issue_c(h1_u,       tid, va);
          issue_c(h1_u + 128, tid, vb);          // 2-deep staging pipeline
          commit(atile[0], tid, va);
          __syncthreads();
          issue_c(h1_u + 256, tid, va);
          L2CHUNK(0, 0);
          commit(atile[1], tid, vb);
          __syncthreads();
          issue_c(h1_u + 384, tid, vb);
          L2CHUNK(1, 1);
          commit(atile[0], tid, va);
          __syncthreads();
          L2CHUNK(2, 0);
          commit(atile[1], tid, vb);
          __syncthreads();
          L2CHUNK(3, 1);
          f32x4 a = acc0 + acc1;
          const int col = n16 * 16 + llo;
          #pragma unroll
          for (int r = 0; r < 4; ++r)
            st_coh16(&h2_s[(lhi * 4 + r) * H_ + col], tobf(fast_tanh(a[r] + bb2)));
        }
        bar_arrive(gflags, gn, ++gen);
        bar_wait(gflags, gen);

        // ==== layer 3: [16x2048]@[2048x512], wave K-split, weights in VGPRs, RK4 ====
        {
          f32x4 acc0 = {0.f, 0.f, 0.f, 0.f}, acc1 = {0.f, 0.f, 0.f, 0.f};
          issue_c(h2_u,       tid, va);
          issue_c(h2_u + 128, tid, vb);
          commit(atile[0], tid, va);
          __syncthreads();
          issue_c(h2_u + 256, tid, va);
          L3CHUNK(0, 0);
          commit(atile[1], tid, vb);
          __syncthreads();
          issue_c(h2_u + 384, tid, vb);
          L3CHUNK(1, 1);
          commit(atile[0], tid, va);
          __syncthreads();
          L3CHUNK(2, 0);
          commit(atile[1], tid, vb);
          __syncthreads();
          L3CHUNK(3, 1);
          f32x4 a = acc0 + acc1;
          #pragma unroll
          for (int r = 0; r < 4; ++r) red[wave][(lhi * 4 + r) * 16 + llo] = a[r];
          __syncthreads();
          if (wave == 0) {
            const float dt = DT_F;
            #pragma unroll
            for (int r = 0; r < 4; ++r) {
              int row = lhi * 4 + r;
              int i = row * 16 + llo;
              float z = red[0][i] + red[1][i] + red[2][i] + red[3][i] + bb3;
              float yv = ytile[i];
              unsigned short* up = &ubuf_s[row * C_ + gn * 16 + llo];
              if (st == 0)      { k1t[i] = z; st_coh16(up, tobf(yv + 0.5f * dt * z)); }
              else if (st == 1) { k2t[i] = z; st_coh16(up, tobf(yv + 0.5f * dt * z)); }
              else if (st == 2) { k3t[i] = z; st_coh16(up, tobf(yv + dt * z)); }
              else {
                float yn = yv + (dt * (1.0f / 6.0f)) * (k1t[i] + 2.f * k2t[i] + 2.f * k3t[i] + z);
                ytile[i] = yn;
                st_coh16(up, tobf(yn));
                if (sub == 2)
                  out[(size_t)(g * M_ + row) * (T_ * C_) + (size_t)(t + 1) * C_ + gn * 16 + llo] = yn;
              }
            }
          }
        }
        bar_arrive(gflags, gn, ++gen);
        bar_wait(gflags, gen);
      }
    }
  }
}

// ---------------- host ----------------
extern "C" void kernel_launch(void* const* d_in, const int* in_sizes, int n_in,
                              void* d_out, int out_size, void* d_ws, size_t ws_size,
                              hipStream_t stream) {
  (void)in_sizes; (void)n_in; (void)out_size; (void)ws_size;
  const float* x  = (const float*)d_in[0];
  const float* W1 = (const float*)d_in[1];
  const float* b1 = (const float*)d_in[2];
  const float* W2 = (const float*)d_in[3];
  const float* b2 = (const float*)d_in[4];
  const float* W3 = (const float*)d_in[5];
  const float* b3 = (const float*)d_in[6];
  float* out = (float*)d_out;
  unsigned char* ws = (unsigned char*)d_ws;

  init_flags_k<<<16, 256, 0, stream>>>((unsigned*)(ws + OFF_FLAGS));
  // W1: K=512 (kblog=4), N=2048 ; W2: K=2048 (kblog=6), N=2048 ; W3: K=2048 (kblog=6), N=512
  swizzle_w_k<<<(C_ * H_) / 256, 256, 0, stream>>>(W1, (unsigned short*)(ws + OFF_W1P), H_, 4);
  swizzle_w_k<<<(H_ * H_) / 256, 256, 0, stream>>>(W2, (unsigned short*)(ws + OFF_W2P), H_, 6);
  swizzle_w_k<<<(H_ * C_) / 256, 256, 0, stream>>>(W3, (unsigned short*)(ws + OFF_W3P), C_, 6);

  ode_persist_k<<<NWG, NTHR, 0, stream>>>(x, b1, b2, b3, out, ws);
}